// Round 1
// baseline (109.763 us; speedup 1.0000x reference)
//
#include <hip/hip_runtime.h>

// GHM loss: focal (ch 0) + GHMR (ch 1..7), 3 scalar outputs.
// Pass 1: grid-stride streaming over pixels; per-thread register
// accumulators (static indexing only) for:
//   acc[0..9]   cumulative bin counts  c_b = #(valid elems with g*10 >= b)
//   acc[10..19] cumulative bin loss    l_b = sum loss over same
//   acc[20]     focal sum
//   acc[21]     valid pixel count
// Block-reduce -> per-block partials in d_ws (no atomics, deterministic).
// Pass 2: 1 block reduces partials and computes the 3 outputs.

#define NQ 22

__global__ __launch_bounds__(256)
void ghm_pass1(const float4* __restrict__ preds, const float4* __restrict__ tgts,
               int n_pix, float* __restrict__ part, int nb) {
    const float MU2 = 0.02f * 0.02f;
    float acc[NQ];
#pragma unroll
    for (int q = 0; q < NQ; ++q) acc[q] = 0.f;

    const int tid = threadIdx.x;
    const int stride = gridDim.x * 256;
    for (int i = blockIdx.x * 256 + tid; i < n_pix; i += stride) {
        const size_t base = 2 * (size_t)i;
        float4 p0 = preds[base];
        float4 p1 = preds[base + 1];
        float4 t0 = tgts[base];
        float4 t1 = tgts[base + 1];

        // focal on channel 0 (y is exactly 0.0 or 1.0)
        float x = p0.x, y = t0.x;
        float x_t = x * (2.f * y - 1.f) + (1.f - y);
        float a_t = 0.25f * (2.f * y - 1.f) + (1.f - y);
        float om = 1.f - x_t;
        acc[20] += -a_t * om * om * __logf(x_t + 1e-5f);

        bool valid = y > 0.1f;
        acc[21] += valid ? 1.f : 0.f;

        float pd[7] = {p0.y, p0.z, p0.w, p1.x, p1.y, p1.z, p1.w};
        float td[7] = {t0.y, t0.z, t0.w, t1.x, t1.y, t1.z, t1.w};
#pragma unroll
        for (int c = 0; c < 7; ++c) {
            float d = pd[c] - td[c];
            float d2 = __builtin_fmaf(d, d, MU2);
            float s = __builtin_sqrtf(d2);
            float loss = s - 0.02f;
            // g*10 = 10*|d|/s ; rcp approx: mis-binning at boundaries is
            // O(1e-6) of elements, negligible vs million-element bins.
            float g10 = 10.f * __builtin_fabsf(d) * __builtin_amdgcn_rcpf(s);
            g10 = valid ? g10 : -1.f;   // invalid fails every predicate
#pragma unroll
            for (int b = 0; b < 10; ++b) {
                bool pb = g10 >= (float)b;
                acc[b]      += pb ? 1.f  : 0.f;
                acc[10 + b] += pb ? loss : 0.f;
            }
        }
    }

    // wave (64-lane) shuffle reduction of all 22 accumulators
#pragma unroll
    for (int q = 0; q < NQ; ++q) {
        float v = acc[q];
        v += __shfl_down(v, 32);
        v += __shfl_down(v, 16);
        v += __shfl_down(v, 8);
        v += __shfl_down(v, 4);
        v += __shfl_down(v, 2);
        v += __shfl_down(v, 1);
        acc[q] = v;
    }

    __shared__ float sm[4][NQ];
    const int wave = tid >> 6, lane = tid & 63;
    if (lane == 0) {
#pragma unroll
        for (int q = 0; q < NQ; ++q) sm[wave][q] = acc[q];
    }
    __syncthreads();
    if (tid < NQ) {
        float v = sm[0][tid] + sm[1][tid] + sm[2][tid] + sm[3][tid];
        part[(size_t)tid * nb + blockIdx.x] = v;   // layout [quantity][block]
    }
}

__global__ __launch_bounds__(256)
void ghm_final(const float* __restrict__ part, int nb,
               float* __restrict__ out, float inv_npix) {
    __shared__ float red[NQ];
    __shared__ float wv[4];
    const int tid = threadIdx.x;

    for (int q = 0; q < NQ; ++q) {
        float v = 0.f;
        for (int i = tid; i < nb; i += 256) v += part[(size_t)q * nb + i];
        v += __shfl_down(v, 32);
        v += __shfl_down(v, 16);
        v += __shfl_down(v, 8);
        v += __shfl_down(v, 4);
        v += __shfl_down(v, 2);
        v += __shfl_down(v, 1);
        if ((tid & 63) == 0) wv[tid >> 6] = v;
        __syncthreads();
        if (tid == 0) red[q] = wv[0] + wv[1] + wv[2] + wv[3];
        __syncthreads();
    }

    if (tid == 0) {
        float tot = fmaxf(red[21], 1.f);
        float n = 0.f, sum = 0.f;
#pragma unroll
        for (int b = 0; b < 10; ++b) {
            float cb = red[b]      - (b < 9 ? red[b + 1]       : 0.f);
            float lb = red[10 + b] - (b < 9 ? red[10 + b + 1]  : 0.f);
            if (cb > 0.f) {
                n += 1.f;
                sum += tot / fmaxf(0.3f * cb, 1e-30f) * lb;
            }
        }
        float reg = sum / fmaxf(n, 1.f) / tot;
        float cls = red[20] * inv_npix;
        out[0] = cls + reg;
        out[1] = reg;
        out[2] = cls;
    }
}

extern "C" void kernel_launch(void* const* d_in, const int* in_sizes, int n_in,
                              void* d_out, int out_size, void* d_ws, size_t ws_size,
                              hipStream_t stream) {
    const float* preds = (const float*)d_in[0];
    const float* tgts  = (const float*)d_in[1];
    const int n_pix = in_sizes[0] / 8;

    size_t nb_max = ws_size / (NQ * sizeof(float));
    int nb = (int)(nb_max < 2048 ? nb_max : 2048);
    if (nb < 1) nb = 1;

    float* part = (float*)d_ws;
    ghm_pass1<<<nb, 256, 0, stream>>>((const float4*)preds, (const float4*)tgts,
                                      n_pix, part, nb);
    ghm_final<<<1, 256, 0, stream>>>(part, nb, (float*)d_out,
                                     1.f / (float)n_pix);
}